// Round 15
// baseline (46.750 us; speedup 1.0000x reference)
//
#include <hip/hip_runtime.h>
#include <cstdint>

// ChamferLoss on MI355X — MFMA edition v10.
// Base = R13 (passing, 44.5us; absmax 0.0). R12/R14 (force MFMA C/D into
// arch-VGPRs via launch_bounds / inline asm) both MISCOMPILED -> abandoned.
// This round: occupancy. R11 measured OccupancyPercent=24% (grid 1024 =
// 4 blocks/CU = 4 waves/SIMD cap, ~2 effective). Change: CHUNK 512->256
// (LDS 32KB->16KB) and targets split into EIGHTHS -> grid 2048 =
// 8 blocks/CU = 8 waves/SIMD. Combine does an 8-way key merge.
//   nn_mfma: e[m,n] = ||t||^2 - 2 q.t as K=16 f16 GEMM via
//     v_mfma_f32_32x32x16_f16 builtin, hi/lo f16 split (11 K-slots, fp32
//     accumulate, |err|~2e-5; layout verified absmax=0.0 since R6).
//     4 B-frags/wave (128 queries): per tile 1 ds_read + 4 MFMA + 4 folds.
//   combine: per-thread 8-way key merge + exact-fp32 scan of the winning
//     32-group (float4 loads), EPS clamp, sqrt, sigma gather, partials.
//   final_reduce: sums 512 partials -> d_out.

#define BLK 256
#define CHUNK 256          // targets staged per buffer (16KB total LDS)
#define NEIGHTH 512        // targets per block (eighth of N)
#define FLT_BIG 3.402823466e38f

typedef _Float16 f16x8 __attribute__((ext_vector_type(8)));
typedef float    f32x16 __attribute__((ext_vector_type(16)));

__device__ __forceinline__ unsigned int f2mono(float f) {
    unsigned int u = __float_as_uint(f);
    return (u & 0x80000000u) ? ~u : (u | 0x80000000u);
}

__device__ __forceinline__ void fsplit(float v, _Float16& h, _Float16& l) {
    h = (_Float16)v;
    l = (_Float16)(v - (float)h);
}

// Fold 16 acc values (fminf tree, compiler-fused to v_min3) + (best,group).
// Strict <: earliest group on tie (first-occurrence argmin semantics).
__device__ __forceinline__ void fold1(const f32x16& c, float& best, int& bg, int g) {
    float t0 = fminf(fminf(c[0], c[1]), c[2]);
    float t1 = fminf(fminf(c[3], c[4]), c[5]);
    float t2 = fminf(fminf(c[6], c[7]), c[8]);
    float t3 = fminf(fminf(c[9], c[10]), c[11]);
    float t4 = fminf(fminf(c[12], c[13]), c[14]);
    float u0 = fminf(fminf(t0, t1), c[15]);
    float u1 = fminf(fminf(t2, t3), t4);
    float v  = fminf(u0, u1);
    bool lt = v < best;
    bg   = lt ? g : bg;
    best = lt ? v : best;
}

__device__ __forceinline__ unsigned long long shflxor_u64_32(unsigned long long v) {
    unsigned lo = (unsigned)v, hi = (unsigned)(v >> 32);
    lo = __shfl_xor(lo, 32, 64);
    hi = __shfl_xor(hi, 32, 64);
    return ((unsigned long long)hi << 32) | lo;
}

__global__ __launch_bounds__(BLK) void nn_mfma(
    const float* __restrict__ K1, const float* __restrict__ K2,
    unsigned long long* __restrict__ pkeys)
{
    // grid 2048: eighth(8) | mtile(8) | b(16) | dir(2)
    int bid = blockIdx.x;
    int egt = bid & 7;
    int mt  = (bid >> 3) & 7;
    int b   = (bid >> 6) & 15;
    int dir = bid >> 10;

    const float* Qp = dir ? K2 : K1;
    const float* Tp = dir ? K1 : K2;
    const float* Qb = Qp + (size_t)b * 3 * 4096;
    const float* Tb = Tp + (size_t)b * 3 * 4096;

    __shared__ f16x8 sA[2][CHUNK / 32][64];   // 16 KB -> 8 blocks/CU

    const int tid = threadIdx.x;
    const int l   = tid & 63;
    const int wid = tid >> 6;
    const int c31 = l & 31;
    const int lh  = l >> 5;

    // ---- per-lane query B-frags: 4 per wave = 128 queries (verified layout) ----
    const int mBase = mt * 512 + wid * 128;
    f16x8 bq[4];
#pragma unroll
    for (int qs = 0; qs < 4; ++qs) {
        int m = mBase + qs * 32 + c31;
        float x = Qb[0 * 4096 + m], y = Qb[1 * 4096 + m], z = Qb[2 * 4096 + m];
        _Float16 Xh, Xl, Yh, Yl, Zh, Zl;
        fsplit(-2.0f * x, Xh, Xl);
        fsplit(-2.0f * y, Yh, Yl);
        fsplit(-2.0f * z, Zh, Zl);
        f16x8 v;
        const _Float16 one = (_Float16)1.0f, zr = (_Float16)0.0f;
        v[0] = lh ? Zh  : Xh;  v[1] = lh ? one : Xl;
        v[2] = lh ? one : Xh;  v[3] = lh ? zr  : Yh;
        v[4] = lh ? zr  : Yl;  v[5] = lh ? zr  : Yh;
        v[6] = lh ? zr  : Zh;  v[7] = lh ? zr  : Zl;
        bq[qs] = v;
    }

    const f32x16 zero = {};
    float best[4] = {FLT_BIG, FLT_BIG, FLT_BIG, FLT_BIG};
    int   bg[4]   = {0, 0, 0, 0};
    const int nBase = egt * NEIGHTH;

    float lx, ly, lz;                          // staged-point registers
#define LOADC(cc) { int n_ = nBase + (cc) * CHUNK + tid;                     \
    lx = Tb[n_]; ly = Tb[4096 + n_]; lz = Tb[2 * 4096 + n_]; }
#define WRITEC(pb) { _Float16 xh,xl,yh,yl,zh,zl,wh,wl;                       \
    fsplit(lx,xh,xl); fsplit(ly,yh,yl); fsplit(lz,zh,zl);                    \
    float w_ = fmaf(lx,lx,fmaf(ly,ly,lz*lz)); fsplit(w_,wh,wl);              \
    const _Float16 zr_ = (_Float16)0.0f;                                     \
    f16x8 a0_ = {xh,xh,xl,yh,yh,yl,zh,zh};                                   \
    f16x8 a1_ = {zl,wh,wl,zr_,zr_,zr_,zr_,zr_};                              \
    sA[pb][tid>>5][tid&31] = a0_; sA[pb][tid>>5][32+(tid&31)] = a1_; }

    LOADC(0); WRITEC(0);
    __syncthreads();

    for (int c = 0; c < 2; ++c) {
        const int p = c & 1;
        const int g0 = egt * 16 + c * 8;       // global group-of-32 base
        if (c < 1) LOADC(1);                   // HBM latency hides under MFMAs

        // compiler-scheduled tile loop: 1 ds_read + 4 MFMA + 4 folds
#pragma unroll 2
        for (int t = 0; t < CHUNK / 32; ++t) {
            f16x8 a = sA[p][t][l];             // ds_read_b128
            f32x16 c0 = __builtin_amdgcn_mfma_f32_32x32x16_f16(a, bq[0], zero, 0, 0, 0);
            f32x16 c1 = __builtin_amdgcn_mfma_f32_32x32x16_f16(a, bq[1], zero, 0, 0, 0);
            f32x16 c2 = __builtin_amdgcn_mfma_f32_32x32x16_f16(a, bq[2], zero, 0, 0, 0);
            f32x16 c3 = __builtin_amdgcn_mfma_f32_32x32x16_f16(a, bq[3], zero, 0, 0, 0);
            fold1(c0, best[0], bg[0], g0 + t);
            fold1(c1, best[1], bg[1], g0 + t);
            fold1(c2, best[2], bg[2], g0 + t);
            fold1(c3, best[3], bg[3], g0 + t);
        }

        if (c < 1) WRITEC(p ^ 1);              // other buffer; reads of it done
        __syncthreads();
    }

    // ---- merge lane^32 (same query column, other row-half); store 2/lane ----
    unsigned long long kk[4];
#pragma unroll
    for (int qs = 0; qs < 4; ++qs) {
        unsigned long long k = ((unsigned long long)f2mono(best[qs]) << 32) |
                               (unsigned)bg[qs];
        unsigned long long o = shflxor_u64_32(k);
        kk[qs] = (o < k) ? o : k;              // both halves now hold the min
    }
    unsigned long long* dst = pkeys + ((size_t)(dir * 8 + egt)) * 65536 +
                              (size_t)b * 4096 + mBase;
    // lane (lh, c31) stores query sets qs = 2*lh and 2*lh+1 (coalesced).
    dst[(2 * lh) * 32 + c31]     = lh ? kk[2] : kk[0];
    dst[(2 * lh + 1) * 32 + c31] = lh ? kk[3] : kk[1];
}

__global__ __launch_bounds__(BLK) void combine_kernel(
    const unsigned long long* __restrict__ pkeys,
    const float* __restrict__ K1, const float* __restrict__ K2,
    const float* __restrict__ s1, const float* __restrict__ s2,
    float* __restrict__ partials)
{
    int gid = blockIdx.x * BLK + (int)threadIdx.x;   // 0..131071
    int dir = gid >> 16;
    int qq  = gid & 65535;
    int b   = qq >> 12, m = qq & 4095;

    const float* Qp = dir ? K2 : K1;
    const float* Tp = dir ? K1 : K2;
    const float* sQ = dir ? s2 : s1;
    const float* sT = dir ? s1 : s2;
    const float scale = 1.0f / 65536.0f;

    // 8-way merge of eighth keys (coalesced u64 loads).
    unsigned long long key = 0xFFFFFFFFFFFFFFFFULL;
#pragma unroll
    for (int q = 0; q < 8; ++q) {
        unsigned long long k = pkeys[(size_t)(dir * 8 + q) * 65536 + qq];
        key = (k < key) ? k : key;
    }
    int g = (int)(key & 0xFFFFFFFFu);

    const float* Qb = Qp + (size_t)b * 3 * 4096;
    const float* Tb = Tp + (size_t)b * 3 * 4096;
    float x = Qb[m], y = Qb[4096 + m], z = Qb[2 * 4096 + m];
    float X = -2.0f * x, Y = -2.0f * y, Z = -2.0f * z;
    float sq1 = fmaf(x, x, fmaf(y, y, z * z));

    // Exact-fp32 serial scan of the winning 32-group; strict < gives
    // first-occurrence argmin. n0 is 128B-aligned -> float4 loads.
    int n0 = g * 32;
    const float4* Tx4 = (const float4*)(Tb + n0);
    const float4* Ty4 = (const float4*)(Tb + 4096 + n0);
    const float4* Tz4 = (const float4*)(Tb + 2 * 4096 + n0);
    float beste = FLT_BIG;
    int bi = n0;
#pragma unroll
    for (int j = 0; j < 8; ++j) {
        float4 xv = Tx4[j], yv = Ty4[j], zv = Tz4[j];
#pragma unroll
        for (int k = 0; k < 4; ++k) {
            float txv = ((const float*)&xv)[k];
            float tyv = ((const float*)&yv)[k];
            float tzv = ((const float*)&zv)[k];
            float w = fmaf(txv, txv, fmaf(tyv, tyv, tzv * tzv));
            float e = fmaf(txv, X, fmaf(tyv, Y, fmaf(tzv, Z, w)));
            bool lt = e < beste;
            bi    = lt ? (n0 + j * 4 + k) : bi;
            beste = lt ? e : beste;
        }
    }

    float d2 = fmaxf(sq1 + beste, 1e-12f);           // reference EPS clamp
    float s = 0.5f * (sQ[qq] + sT[b * 4096 + bi]);
    float v = (logf(s) + sqrtf(d2) / s) * scale;

    __shared__ float red[BLK];
    red[threadIdx.x] = v;
    __syncthreads();
    for (int st = BLK / 2; st > 0; st >>= 1) {
        if ((int)threadIdx.x < st) red[threadIdx.x] += red[threadIdx.x + st];
        __syncthreads();
    }
    if (threadIdx.x == 0) partials[blockIdx.x] = red[0];
}

__global__ __launch_bounds__(256) void final_reduce(
    const float* __restrict__ partials, float* __restrict__ out, int n)
{
    __shared__ float red[256];
    int t = threadIdx.x;
    float a = 0.0f;
    for (int i = t; i < n; i += 256) a += partials[i];
    red[t] = a;
    __syncthreads();
    for (int st = 128; st > 0; st >>= 1) {
        if (t < st) red[t] += red[t + st];
        __syncthreads();
    }
    if (t == 0) out[0] = red[0];
}

extern "C" void kernel_launch(void* const* d_in, const int* in_sizes, int n_in,
                              void* d_out, int out_size, void* d_ws, size_t ws_size,
                              hipStream_t stream) {
    const float* k1 = (const float*)d_in[0];   // (B,3,M)
    const float* k2 = (const float*)d_in[1];   // (B,3,N)
    const float* s1 = (const float*)d_in[2];   // (B,M)
    const float* s2 = (const float*)d_in[3];   // (B,N)
    float* out = (float*)d_out;

    unsigned long long* pkeys = (unsigned long long*)d_ws;   // 16 * 65536 keys
    float* partials = (float*)(pkeys + (size_t)16 * 65536);  // 512 floats

    nn_mfma<<<2048, BLK, 0, stream>>>(k1, k2, pkeys);
    combine_kernel<<<512, BLK, 0, stream>>>(pkeys, k1, k2, s1, s2, partials);
    final_reduce<<<1, 256, 0, stream>>>(partials, out, 512);
}